// Round 2
// baseline (2406.626 us; speedup 1.0000x reference)
//
#include <hip/hip_runtime.h>

// LSTM (B=512, T=1024, I=64, H=128) + FC(128->256->1), fp32 in/out.
// MFMA rewrite: gates[512 x 2] = W_cat[512 x 192] . v[2 x 192] per step,
// W_cat = [W_ih | W_hh], v = [x_t | h]. 3-term bf16 split for fp32-class
// precision: Whi*vhi + Whi*vlo + Wlo*vhi (lo*lo term ~2^-18, dropped).
// 256 blocks x 512 threads, 1 block/CU, 2 batch rows/block.
// Wave w owns M-tiles {w, w+8, w+16, w+24} == one 16-row tile per gate type;
// A-frags (weights) stationary in VGPRs (~192), B-frags from LDS per step.

#define T_STEPS 1024
#define ISZ 64
#define HSZ 128
#define KTOT 192
#define NGATE 512
#define NTH 512
#define BCHUNK 2

typedef short bf16x8 __attribute__((ext_vector_type(8)));
typedef float f32x4  __attribute__((ext_vector_type(4)));

__device__ __forceinline__ short f32_to_bf16_rn(float f) {
    union { float f; unsigned u; } v; v.f = f;
    unsigned r = v.u + 0x7FFFu + ((v.u >> 16) & 1u);
    return (short)(r >> 16);
}
__device__ __forceinline__ float bf16_to_f32(short h) {
    union { unsigned u; float f; } v;
    v.u = ((unsigned)(unsigned short)h) << 16;
    return v.f;
}

__device__ __forceinline__ float fast_sigmoid(float x) {
    return 1.0f / (1.0f + __expf(-x));
}
__device__ __forceinline__ float fast_tanh(float x) {
    float xc = fminf(fmaxf(x, -15.0f), 15.0f);
    float u = __expf(2.0f * xc);
    return (u - 1.0f) / (u + 1.0f);
}

__global__ __launch_bounds__(NTH, 2)  // 2 waves/EU -> VGPR cap 256 (need ~250)
void lstm_mfma_kernel(const float* __restrict__ x,
                      const float* __restrict__ W_ih,
                      const float* __restrict__ W_hh,
                      const float* __restrict__ b_ih,
                      const float* __restrict__ b_hh,
                      const float* __restrict__ W1,
                      const float* __restrict__ b1,
                      const float* __restrict__ W2,
                      const float* __restrict__ b2,
                      float* __restrict__ out)
{
    __shared__ __align__(16) short vhi[BCHUNK][KTOT];   // bf16 hi of [x_t | h]
    __shared__ __align__(16) short vlo[BCHUNK][KTOT];   // bf16 lo
    __shared__ __align__(16) float gbuf[BCHUNK][NGATE]; // activated gates
    __shared__ __align__(16) float biasC[NGATE];
    __shared__ __align__(16) float hbuf[BCHUNK][HSZ];   // fp32 h (for FC head)
    __shared__ float red[BCHUNK][4];

    const int tid  = threadIdx.x;
    const int lane = tid & 63;
    const int w    = tid >> 6;        // wave 0..7
    const int mrow = lane & 15;       // A-frag row / D col select
    const int kb   = lane >> 4;       // k-block 0..3 (k = kb*8 + j)
    const int rowbase = kb << 2;      // D rows rowbase..rowbase+3
    const int b0   = blockIdx.x * BCHUNK;

    // ---- one-time: load & split weights into stationary A-frags ----
    // tile i of this wave covers gate rows g = 128*i + 16*w + m  (type == i)
    bf16x8 whi[4][6], wlo[4][6];
    #pragma unroll
    for (int i = 0; i < 4; ++i) {
        const int g = 128 * i + 16 * w + mrow;
        #pragma unroll
        for (int ks = 0; ks < 6; ++ks) {
            #pragma unroll
            for (int j = 0; j < 8; ++j) {
                const int k = ks * 32 + kb * 8 + j;
                float val = (k < ISZ) ? W_ih[(size_t)g * ISZ + k]
                                      : W_hh[(size_t)g * HSZ + (k - ISZ)];
                short hi = f32_to_bf16_rn(val);
                short lo = f32_to_bf16_rn(val - bf16_to_f32(hi));
                whi[i][ks][j] = hi;
                wlo[i][ks][j] = lo;
            }
        }
    }

    // ---- pre-loop staging ----
    biasC[tid] = b_ih[tid] + b_hh[tid];
    if (tid < 256) {  // zero h-part of v
        int b = tid >> 7, k = ISZ + (tid & 127);
        vhi[b][k] = 0; vlo[b][k] = 0;
    }
    const int lx = tid - 256, bx = (lx >> 6) & 1, ix = lx & 63;
    if (tid >= 256 && tid < 384) {    // stage x(t=0)
        float xv = x[((size_t)(b0 + bx) * T_STEPS + 0) * ISZ + ix];
        short hi = f32_to_bf16_rn(xv);
        vhi[bx][ix] = hi;
        vlo[bx][ix] = f32_to_bf16_rn(xv - bf16_to_f32(hi));
    }
    float c = 0.0f;                   // cell state: thread tid<256 owns (j=tid>>1, b=tid&1)
    __syncthreads();

    const short* vh_row = &vhi[mrow & 1][0];  // B col n reads v[n&1] (cols 2..15 unused)
    const short* vl_row = &vlo[mrow & 1][0];
    const int fragoff = kb * 8;

    f32x4 acc[4];
    #pragma unroll
    for (int i = 0; i < 4; ++i)
        acc[i] = *(const f32x4*)&biasC[128 * i + 16 * w + rowbase];

    #pragma unroll 1
    for (int t = 0; t < T_STEPS; ++t) {
        // x(t+1) prefetch (waves 4-5), consumed after barrier A
        float xp = 0.0f;
        const bool pfx = (tid >= 256) && (tid < 384) && (t + 1 < T_STEPS);
        if (pfx)
            xp = x[((size_t)(b0 + bx) * T_STEPS + (t + 1)) * ISZ + ix];

        // ---- MFMA phase: gates = W_cat . v  (3-term split) ----
        #pragma unroll
        for (int ks = 0; ks < 6; ++ks) {
            bf16x8 bh = *(const bf16x8*)(vh_row + ks * 32 + fragoff);
            bf16x8 bl = *(const bf16x8*)(vl_row + ks * 32 + fragoff);
            #pragma unroll
            for (int i = 0; i < 4; ++i)
                acc[i] = __builtin_amdgcn_mfma_f32_16x16x32_bf16(whi[i][ks], bh, acc[i], 0, 0, 0);
            #pragma unroll
            for (int i = 0; i < 4; ++i)
                acc[i] = __builtin_amdgcn_mfma_f32_16x16x32_bf16(whi[i][ks], bl, acc[i], 0, 0, 0);
            #pragma unroll
            for (int i = 0; i < 4; ++i)
                acc[i] = __builtin_amdgcn_mfma_f32_16x16x32_bf16(wlo[i][ks], bh, acc[i], 0, 0, 0);
        }

        // ---- epilogue: activate + write gbuf (D: row=(lane>>4)*4+r, col=lane&15) ----
        if (mrow < 2) {
            #pragma unroll
            for (int i = 0; i < 4; ++i) {
                #pragma unroll
                for (int r = 0; r < 4; ++r) {
                    float gv = acc[i][r];
                    float av = (i == 2) ? fast_tanh(gv) : fast_sigmoid(gv);
                    gbuf[mrow][128 * i + 16 * w + rowbase + r] = av;
                }
            }
        }
        // re-init acc with bias for next step
        #pragma unroll
        for (int i = 0; i < 4; ++i)
            acc[i] = *(const f32x4*)&biasC[128 * i + 16 * w + rowbase];
        __syncthreads();  // A: gbuf ready; all v reads done

        // ---- c/h update (threads 0..255) + x store (256..383) ----
        if (tid < 256) {
            const int j = tid >> 1, b = tid & 1;
            float ig = gbuf[b][j];
            float fg = gbuf[b][HSZ + j];
            float gg = gbuf[b][2 * HSZ + j];
            float og = gbuf[b][3 * HSZ + j];
            c = fmaf(fg, c, ig * gg);
            float h = og * fast_tanh(c);
            short hh = f32_to_bf16_rn(h);
            vhi[b][ISZ + j] = hh;
            vlo[b][ISZ + j] = f32_to_bf16_rn(h - bf16_to_f32(hh));
            hbuf[b][j] = h;
        } else if (pfx) {
            short xh = f32_to_bf16_rn(xp);
            vhi[bx][ix] = xh;
            vlo[bx][ix] = f32_to_bf16_rn(xp - bf16_to_f32(xh));
        }
        __syncthreads();  // B: v ready for t+1
    }

    // ---- FC head: out[b] = W2 . (W1 h + b1) + b2 ----
    {
        const int b = tid >> 8;
        const int m = tid & 255;
        const float4* w1r = reinterpret_cast<const float4*>(W1 + (size_t)m * HSZ);
        const float4* hr = reinterpret_cast<const float4*>(hbuf[b]);
        float a2 = 0.0f;
        #pragma unroll
        for (int k = 0; k < HSZ / 4; ++k) {
            float4 wv = w1r[k];
            float4 hv = hr[k];
            a2 = fmaf(wv.x, hv.x, a2);
            a2 = fmaf(wv.y, hv.y, a2);
            a2 = fmaf(wv.z, hv.z, a2);
            a2 = fmaf(wv.w, hv.w, a2);
        }
        float z = (a2 + b1[m]) * W2[m];
        #pragma unroll
        for (int off = 32; off >= 1; off >>= 1)
            z += __shfl_down(z, off, 64);
        if ((tid & 63) == 0) red[b][(tid >> 6) & 3] = z;
    }
    __syncthreads();
    if (tid == 0)   out[b0]     = red[0][0] + red[0][1] + red[0][2] + red[0][3] + b2[0];
    if (tid == 256) out[b0 + 1] = red[1][0] + red[1][1] + red[1][2] + red[1][3] + b2[0];
}

extern "C" void kernel_launch(void* const* d_in, const int* in_sizes, int n_in,
                              void* d_out, int out_size, void* d_ws, size_t ws_size,
                              hipStream_t stream) {
    const float* x    = (const float*)d_in[0];
    const float* W_ih = (const float*)d_in[1];
    const float* W_hh = (const float*)d_in[2];
    const float* b_ih = (const float*)d_in[3];
    const float* b_hh = (const float*)d_in[4];
    const float* W1   = (const float*)d_in[5];
    const float* b1   = (const float*)d_in[6];
    const float* W2   = (const float*)d_in[7];
    const float* b2   = (const float*)d_in[8];
    float* out = (float*)d_out;

    lstm_mfma_kernel<<<dim3(512 / BCHUNK), dim3(NTH), 0, stream>>>(
        x, W_ih, W_hh, b_ih, b_hh, W1, b1, W2, b2, out);
}